// Round 5
// baseline (110.857 us; speedup 1.0000x reference)
//
#include <hip/hip_runtime.h>
#include <stdint.h>

// LIF spiking scan: x[B=8, S=2048, H=4096] f32 -> spikes[B,S,H] f32.
// 512 waves (2/CU, structural). R4 insight: compute and memory were
// ALTERNATING (prefetch+flush issued after the serial LIF chain), leaving
// the memory system under-run during compute. Fix: 3-deep x-tile pipeline
// and hoist all memory issue ahead of compute:
//   per iter: wait(counted vmcnt) -> issue L(t+2) -> flush F(t-1) -> compute t
// => 48 VMEM ops (48KB) in flight per wave across the compute phase.
// Bit-exact vs numpy: unfused __fmul_rn+__fadd_rn leak (FMA contraction
// flips borderline threshold comparisons -> chaotic spike flips).

#define S_LEN 2048
#define H_DIM 4096
#define TS 64              // timesteps per tile
#define NT (S_LEN / TS)    // 32 tiles

typedef __attribute__((address_space(3))) uint32_t lds_u32;
typedef __attribute__((address_space(1))) const uint32_t gbl_u32;
typedef float f32x4 __attribute__((ext_vector_type(4)));

__global__ __launch_bounds__(64, 1) void lif_kernel(
    const float* __restrict__ x,
    const float* __restrict__ thr_p,
    const float* __restrict__ decay_p,
    float* __restrict__ out)
{
    __shared__ __attribute__((aligned(16))) float xbuf[3][TS][64];  // 48 KB
    __shared__ __attribute__((aligned(16))) float obuf[2][TS][64];  // 32 KB
    // 80 KB total -> exactly 2 single-wave blocks per CU (160 KB pool).

    const int lane = threadIdx.x;            // 0..63
    const int b    = blockIdx.x >> 6;        // 0..7
    const int h0   = (blockIdx.x & 63) * 64; // h-tile origin

    const float thr   = thr_p[0];
    const float decay = decay_p[0];

    const size_t seq_base = (size_t)b * S_LEN * H_DIM;
    const int lrow = lane >> 4;              // 0..3  (row within 4-row group)
    const int lcol = (lane & 15) * 4;        // 0..60 (col, 4 floats)
    // per-lane global source/dest for wide ops (4 rows x 64 h per instr)
    const float* gsrc0 = x   + seq_base + (size_t)lrow * H_DIM + h0 + lcol;
    float*       gdst0 = out + seq_base + (size_t)lrow * H_DIM + h0 + lcol;

    // Drain the scalar param loads so vmcnt bookkeeping below starts at 0.
    asm volatile("s_waitcnt vmcnt(0) lgkmcnt(0)" ::: "memory");

    // 16 width-16 global->LDS loads for tile t into xbuf[buf] (1KB per op).
    // LDS dest is wave-uniform base + lane*16 -> lands as [s_local][h_local].
    auto issue_tile = [&](int t, int buf) {
        const float* g = gsrc0 + (size_t)t * TS * H_DIM;
#pragma unroll
        for (int k = 0; k < 16; ++k) {
            __builtin_amdgcn_global_load_lds(
                (gbl_u32*)(g + (size_t)k * 4 * H_DIM),
                (lds_u32*)&xbuf[buf][k * 4][0],
                16, 0, 0);
        }
    };

    // 16x 1KB nontemporal dwordx4 stores from obuf[t&1] -> out tile t.
    auto flush_tile = [&](int t) {
        float*       gd   = gdst0 + (size_t)t * TS * H_DIM;
        const float* lsrc = &obuf[t & 1][0][0];
#pragma unroll
        for (int k = 0; k < 16; ++k) {
            const f32x4 v = *(const f32x4*)(lsrc + k * 256 + lane * 4);
            __builtin_nontemporal_store(v, (f32x4*)(gd + (size_t)k * 4 * H_DIM));
        }
    };

    float mem = 0.0f;
    float ref = 0.0f;

    issue_tile(0, 0);
    issue_tile(1, 1);

    for (int t = 0; t < NT; ++t) {
        // Wait for tile t's 16 loads. Newer outstanding ops (issue order
        // L0 L1 | L2 | L3 F0 | L4 F1 | ... | L(t+2) F(t-1) | ...):
        //   t<=1:     L(t+1)                  -> vmcnt(16)
        //   t==2:     L3,F0                   -> vmcnt(32)
        //   t==NT-1:  F(NT-4)? none; F28,F29  -> vmcnt(32)
        //   else:     F(t-3),L(t+1),F(t-2)... -> vmcnt(48)
        if (t <= 1)                     asm volatile("s_waitcnt vmcnt(16)" ::: "memory");
        else if (t == 2 || t == NT - 1) asm volatile("s_waitcnt vmcnt(32)" ::: "memory");
        else                            asm volatile("s_waitcnt vmcnt(48)" ::: "memory");
        __builtin_amdgcn_sched_barrier(0);

        // All memory issue happens BEFORE compute so it drains during the
        // serial LIF chain.
        if (t + 2 < NT) issue_tile(t + 2, (t + 2) % 3);
        if (t >= 1)     flush_tile(t - 1);

        // Compute 64 timesteps from xbuf[t%3], spikes -> obuf[t&1].
        const float* xb = &xbuf[t % 3][0][0];
        float*       ob = &obuf[t & 1][0][0];
#pragma unroll
        for (int s = 0; s < TS; ++s) {
            const float xv   = xb[s * 64 + lane];
            const float memn = __fadd_rn(__fmul_rn(decay, mem), xv);  // 2 roundings
            ref = fmaxf(__fadd_rn(ref, -1.0f), 0.0f);                 // clamp(ref-1,0)
            const bool spk_b = (ref == 0.0f) & (memn > thr);
            mem = spk_b ? 0.0f : memn;                                // exact reset
            ref = __fadd_rn(ref, spk_b ? 5.0f : 0.0f);                // exact
            ob[s * 64 + lane] = spk_b ? 1.0f : 0.0f;
        }

        __builtin_amdgcn_wave_barrier();
    }

    // Epilogue: last tile's spikes.
    flush_tile(NT - 1);
}

extern "C" void kernel_launch(void* const* d_in, const int* in_sizes, int n_in,
                              void* d_out, int out_size, void* d_ws, size_t ws_size,
                              hipStream_t stream) {
    const float* x     = (const float*)d_in[0];
    const float* thr   = (const float*)d_in[1];
    const float* decay = (const float*)d_in[2];
    float*       out   = (float*)d_out;

    // 512 blocks x 64 threads = 32768 sequences; 2 single-wave blocks per CU.
    lif_kernel<<<dim3(512), dim3(64), 0, stream>>>(x, thr, decay, out);
}

// Round 6
// 81.022 us; speedup vs baseline: 1.3682x; 1.3682x over previous
//
#include <hip/hip_runtime.h>
#include <stdint.h>

// LIF spiking scan: x[B=8, S=2048, H=4096] f32 -> spikes[B,S,H] f32.
// R5 post-mortem: deeper buffering didn't help -- the single wave per tile
// serializes {vmcnt wait, 32-op VMEM issue, flush lgkm chains, 64-step LIF
// dependent chain}. Fix: PRODUCER/CONSUMER WAVE SPECIALIZATION.
//   block = 128 thr = 2 waves per h-tile:
//     wave 0: compute only. Never waits vmcnt; syncs via raw s_barrier.
//     wave 1: DMA only. global_load_lds prefetch L(t+2), counted vmcnt
//             waits for L(t) (never drain-to-0), obuf->global flush F(t-1).
//   vmcnt is per-wave => DMA stalls never block the LIF chain.
// 512 blocks -> 2 blocks/CU (80KB LDS each), 4 waves/CU on 4 SIMDs.
// Bit-exact vs numpy: unfused __fmul_rn+__fadd_rn leak (FMA contraction
// flips borderline threshold comparisons -> chaotic spike flips).

#define S_LEN 2048
#define H_DIM 4096
#define TS 64              // timesteps per tile
#define NT (S_LEN / TS)    // 32 tiles

typedef __attribute__((address_space(3))) uint32_t lds_u32;
typedef __attribute__((address_space(1))) const uint32_t gbl_u32;
typedef float f32x4 __attribute__((ext_vector_type(4)));

__global__ __launch_bounds__(128, 1) void lif_kernel(
    const float* __restrict__ x,
    const float* __restrict__ thr_p,
    const float* __restrict__ decay_p,
    float* __restrict__ out)
{
    __shared__ __attribute__((aligned(16))) float xbuf[3][TS][64];  // 48 KB
    __shared__ __attribute__((aligned(16))) float obuf[2][TS][64];  // 32 KB
    // 80 KB total -> exactly 2 blocks/CU (160 KB pool).

    const int lane = threadIdx.x & 63;
    const int wid  = threadIdx.x >> 6;       // 0 = compute, 1 = DMA
    const int b    = blockIdx.x >> 6;        // 0..7
    const int h0   = (blockIdx.x & 63) * 64; // h-tile origin
    const size_t seq_base = (size_t)b * S_LEN * H_DIM;

    if (wid == 1) {
        // ---------------- DMA wave ----------------
        const int lrow = lane >> 4;              // 0..3
        const int lcol = (lane & 15) * 4;        // 0..60
        const float* gsrc0 = x   + seq_base + (size_t)lrow * H_DIM + h0 + lcol;
        float*       gdst0 = out + seq_base + (size_t)lrow * H_DIM + h0 + lcol;

        // Drain anything outstanding so vmcnt bookkeeping starts at 0.
        asm volatile("s_waitcnt vmcnt(0) lgkmcnt(0)" ::: "memory");

        // 16 width-16 global->LDS loads (1 KB/op); LDS dest wave-uniform
        // base + lane*16 lands as [s_local][h_local].
        auto issue_tile = [&](int t, int buf) {
            const float* g = gsrc0 + (size_t)t * TS * H_DIM;
#pragma unroll
            for (int k = 0; k < 16; ++k) {
                __builtin_amdgcn_global_load_lds(
                    (gbl_u32*)(g + (size_t)k * 4 * H_DIM),
                    (lds_u32*)&xbuf[buf][k * 4][0],
                    16, 0, 0);
            }
        };
        // 16x 1KB nontemporal dwordx4 stores from obuf[t&1] -> out tile t.
        auto flush_tile = [&](int t) {
            float*       gd   = gdst0 + (size_t)t * TS * H_DIM;
            const float* lsrc = &obuf[t & 1][0][0];
#pragma unroll
            for (int k = 0; k < 16; ++k) {
                const f32x4 v = *(const f32x4*)(lsrc + k * 256 + lane * 4);
                __builtin_nontemporal_store(v, (f32x4*)(gd + (size_t)k * 4 * H_DIM));
            }
        };

        issue_tile(0, 0);
        issue_tile(1, 1);

        for (int t = 0; t < NT; ++t) {
            // Wait for L(t). Issue order: L0 L1 | L2 | L3 F0 | L4 F1 | ...
            // newer-than-L(t) counts: t<=1:16  t==2:32  t==NT-1:32  else:48
            if (t <= 1)                     asm volatile("s_waitcnt vmcnt(16)" ::: "memory");
            else if (t == 2 || t == NT - 1) asm volatile("s_waitcnt vmcnt(32)" ::: "memory");
            else                            asm volatile("s_waitcnt vmcnt(48)" ::: "memory");

            asm volatile("s_barrier" ::: "memory");   // release compute for tile t

            if (t + 2 < NT) issue_tile(t + 2, (t + 2) % 3);
            if (t >= 1)     flush_tile(t - 1);        // obuf written iter t-1, lgkm-drained
        }

        asm volatile("s_barrier" ::: "memory");       // compute finished tile NT-1
        flush_tile(NT - 1);
    } else {
        // ---------------- compute wave ----------------
        const float thr   = thr_p[0];
        const float decay = decay_p[0];

        float mem = 0.0f;
        float ref = 0.0f;

        for (int t = 0; t < NT; ++t) {
            asm volatile("s_barrier" ::: "memory");   // tile t ready in xbuf[t%3]

            const float* xb = &xbuf[t % 3][0][0];
            float*       ob = &obuf[t & 1][0][0];
#pragma unroll
            for (int s = 0; s < TS; ++s) {
                const float xv   = xb[s * 64 + lane];
                const float memn = __fadd_rn(__fmul_rn(decay, mem), xv);  // 2 roundings
                ref = fmaxf(__fadd_rn(ref, -1.0f), 0.0f);                 // clamp(ref-1,0)
                const bool spk_b = (ref == 0.0f) & (memn > thr);
                mem = spk_b ? 0.0f : memn;                                // exact reset
                ref = __fadd_rn(ref, spk_b ? 5.0f : 0.0f);                // exact
                ob[s * 64 + lane] = spk_b ? 1.0f : 0.0f;
            }
            // obuf writes (and xbuf reads) retired before next barrier.
            asm volatile("s_waitcnt lgkmcnt(0)" ::: "memory");
        }
        asm volatile("s_barrier" ::: "memory");       // final: release last flush
    }
}

extern "C" void kernel_launch(void* const* d_in, const int* in_sizes, int n_in,
                              void* d_out, int out_size, void* d_ws, size_t ws_size,
                              hipStream_t stream) {
    const float* x     = (const float*)d_in[0];
    const float* thr   = (const float*)d_in[1];
    const float* decay = (const float*)d_in[2];
    float*       out   = (float*)d_out;

    // 512 blocks x 128 threads (compute wave + DMA wave per h-tile);
    // 2 blocks/CU, 4 waves/CU.
    lif_kernel<<<dim3(512), dim3(128), 0, stream>>>(x, thr, decay, out);
}